// Round 7
// baseline (205.482 us; speedup 1.0000x reference)
//
#include <hip/hip_runtime.h>

#define BB 8
#define SS 4096
#define DD 128

typedef __attribute__((ext_vector_type(8))) short v8s;
typedef __attribute__((ext_vector_type(4))) float v4f;
typedef __attribute__((ext_vector_type(16))) float v16f;

__device__ __forceinline__ unsigned short f2bf(float f) {
    unsigned int u = __float_as_uint(f);
    u += 0x7fffu + ((u >> 16) & 1u);
    return (unsigned short)(u >> 16);
}
// pack bf16(a) | bf16(b)<<16, round-half-up, via v_perm
__device__ __forceinline__ unsigned int pk_bf16(float a, float b) {
    unsigned int ua = __float_as_uint(a) + 0x8000u;
    unsigned int ub = __float_as_uint(b) + 0x8000u;
    return __builtin_amdgcn_perm(ub, ua, 0x07060302u);
}

#if !defined(__HIP_DEVICE_COMPILE__)
#define MFMA16(a, b, c) (c)
#define MFMA32(a, b, c) (c)
#define GLDS16(g, l)
#define WAITVM(n)
#define WAITLGKM()
#define BAR()
#else
#define MFMA16(a, b, c) __builtin_amdgcn_mfma_f32_16x16x32_bf16((a), (b), (c), 0, 0, 0)
#define MFMA32(a, b, c) __builtin_amdgcn_mfma_f32_32x32x16_bf16((a), (b), (c), 0, 0, 0)
// async global->LDS DMA, 16B/lane, LDS dest = uniform base + lane*16
#define GLDS16(g, l)                                                         \
    __builtin_amdgcn_global_load_lds(                                        \
        (const __attribute__((address_space(1))) unsigned int*)(g),          \
        (__attribute__((address_space(3))) unsigned int*)(l), 16, 0, 0)
#define WAITVM(n) asm volatile("s_waitcnt vmcnt(" #n ")" ::: "memory")
#define WAITLGKM() asm volatile("s_waitcnt lgkmcnt(0)" ::: "memory")
#define BAR()                                                                \
    do {                                                                     \
        asm volatile("" ::: "memory");                                       \
        __builtin_amdgcn_s_barrier();                                        \
        __builtin_amdgcn_sched_barrier(0);                                   \
        asm volatile("" ::: "memory");                                       \
    } while (0)
#endif

#if !defined(__HIP_DEVICE_COMPILE__)
#define EXP2F(x) exp2f(x)
#elif __has_builtin(__builtin_amdgcn_exp2f)
#define EXP2F(x) __builtin_amdgcn_exp2f(x)
#else
#define EXP2F(x) exp2f(x)
#endif

// (1/sqrt(128)) * log2(e): softmax in 2^x domain (no max subtraction: scores
// in log2 domain ~N(0,~6^2), fp32 overflow needs >20 sigma; the uniform
// scale cancels exactly in O/l). Both K-halves share the scale -> merging
// partial O/l is a plain add.
#define QSCALE 0.12751743f

// ---------------- fused kernel: proj (phase 1) + flash (phase 2) -----------
// One launch. Grid 256 x 512 = 1 block/CU (guide-sanctioned co-residency:
// __launch_bounds__(512,2), grid == CU count) -> hand-rolled device-scope
// grid barrier between phases (bar[] zeroed by hipMemsetAsync each launch).
// Phase 1: block (b,qt) projects ITS OWN 128 rows: x read once, pe trig
// once (r6 proj did both 3x), W transposed in-LDS per block; q stays
// on-chip in swizzled LDS (no global round trip); k/vT -> workspace
// (consumers are same-XCD: b = bid&7). Phase 2: r6-verified flash verbatim,
// qf from LDS. LDS: 64K (k) + 64K (v) + 32K (q) = exactly 160 KiB; phase-1
// w_lds/o_lds alias the k/v regions, epilogue xl aliases q_lds.
#define HKEYS 2048
#define NT 32             // 64-key tiles per half
__global__ __launch_bounds__(512, 2) void fused_kernel(
    const float* __restrict__ x,
    const float* __restrict__ Wq, const float* __restrict__ bq,
    const float* __restrict__ Wk, const float* __restrict__ bk,
    const float* __restrict__ Wv, const float* __restrict__ bv,
    unsigned short* __restrict__ ko, unsigned short* __restrict__ vo,
    float* __restrict__ outp, unsigned int* bar)
{
    __shared__ __attribute__((aligned(16))) unsigned short k_lds[2][2][8192]; // 64 KB
    __shared__ __attribute__((aligned(16))) unsigned short v_lds[2][2][8192]; // 64 KB
    __shared__ __attribute__((aligned(16))) unsigned short q_lds[16384];      // 32 KB

    const int tid = threadIdx.x;
    const int wave = tid >> 6;
    const int lane = tid & 63;
    const int hi = lane >> 5;
    const int l31 = lane & 31;
    const int bid = blockIdx.x;
    const int b = bid & 7;         // batch -> XCD pinning
    const int qt = bid >> 3;
    const int qbase = qt * 128;

    // ================= phase 1: projections for this block's 128 rows ======
    {
        const int quad = lane >> 4;
        const int l15 = lane & 15;
        const int xrow = qbase + wave * 16 + l15;     // seq position 0..4095

        // x + positional encoding -> bf16 A-fragments (once for all 3 mats)
        v8s af[4];
#pragma unroll
        for (int kc = 0; kc < 4; ++kc) {
            const int kbase = kc * 32 + quad * 8;
            const v4f* xp = (const v4f*)(x + (size_t)(b * SS + xrow) * DD + kbase);
            v4f x0 = xp[0], x1 = xp[1];
            float p[8];
#pragma unroll
            for (int j = 0; j < 8; j += 2) {
                float freq = __expf((float)(kbase + j) * -0.07195578415606394f);
                float arg = (float)xrow * freq;
                p[j] = __sinf(arg);
                p[j + 1] = __cosf(arg);
            }
            v8s a;
#pragma unroll
            for (int j = 0; j < 4; ++j) a[j] = (short)f2bf(x0[j] + p[j]);
#pragma unroll
            for (int j = 0; j < 4; ++j) a[4 + j] = (short)f2bf(x1[j] + p[4 + j]);
            af[kc] = a;
        }

        unsigned short* w_lds = &k_lds[0][0][0];      // 128x136 bf16 = 34816 B
        unsigned short* o_lds = &v_lds[0][0][0];      // 128x136 bf16 = 34816 B
        const int quadp = ((quad & 1) << 1) | (quad >> 1);

#pragma unroll 1
        for (int m = 0; m < 3; ++m) {
            const float* W = (m == 0) ? Wq : (m == 1) ? Wk : Wv;
            const float* bias = (m == 0) ? bq : (m == 1) ? bk : bv;
            __syncthreads();   // previous users of w_lds/o_lds done
            // stage W transposed: w_lds[n][k] = bf16(W[k][n])
#pragma unroll
            for (int j = 0; j < 32; ++j) {
                int id = j * 512 + tid;
                int n = id >> 7, k2 = id & 127;
                w_lds[n * 136 + k2] = f2bf(W[k2 * 128 + n]);
            }
            __syncthreads();

#pragma unroll
            for (int nb = 0; nb < 8; ++nb) {
                const int col = nb * 16 + l15;
                v4f acc = {0.f, 0.f, 0.f, 0.f};
#pragma unroll
                for (int kc = 0; kc < 4; ++kc) {
                    v8s bf = *(const v8s*)(w_lds + col * 136 + kc * 32 + quad * 8);
                    acc = MFMA16(af[kc], bf, acc);
                }
                float bval = bias[col];
#pragma unroll
                for (int reg = 0; reg < 4; ++reg) {
                    float val = acc[reg] + bval;
                    if (m == 0) {
                        // q -> swizzled LDS (chunk c -> c ^ (row&7))
                        int row = wave * 16 + quad * 4 + reg;
                        int boff = row * 256 + ((col * 2) ^ ((row & 7) << 4));
                        *(unsigned short*)((char*)q_lds + boff) =
                            f2bf(val * QSCALE);
                    } else if (m == 1) {
                        int lr = wave * 16 + quad * 4 + reg;
                        o_lds[lr * 136 + col] = f2bf(val);
                    } else {
                        int plr = wave * 16 + quadp * 4 + reg;  // frag-order key
                        o_lds[col * 136 + plr] = f2bf(val);     // transpose
                    }
                }
            }
            if (m == 1) {
                __syncthreads();
#pragma unroll
                for (int it = 0; it < 4; ++it) {
                    int id = it * 512 + tid;
                    int r = id >> 4, c8 = id & 15;
                    *(v8s*)(ko + (size_t)(b * SS + qbase + r) * DD + c8 * 8) =
                        *(const v8s*)(o_lds + r * 136 + c8 * 8);
                }
            } else if (m == 2) {
                __syncthreads();
#pragma unroll
                for (int it = 0; it < 4; ++it) {
                    int id = it * 512 + tid;
                    int a = id >> 4, c = id & 15;
                    *(v8s*)(vo + (size_t)(b * DD + a) * SS + qbase + c * 8) =
                        *(const v8s*)(o_lds + a * 136 + c * 8);
                }
            }
        }
    }

    // ================= grid barrier (all 256 blocks co-resident) ===========
    WAITVM(0);
    __syncthreads();
    if (tid == 0) {
        __threadfence();
        unsigned int gen = __hip_atomic_load(&bar[1], __ATOMIC_RELAXED,
                                             __HIP_MEMORY_SCOPE_AGENT);
        unsigned int old = __hip_atomic_fetch_add(&bar[0], 1u, __ATOMIC_ACQ_REL,
                                                  __HIP_MEMORY_SCOPE_AGENT);
        if (old == 255u) {
            __hip_atomic_store(&bar[0], 0u, __ATOMIC_RELAXED,
                               __HIP_MEMORY_SCOPE_AGENT);
            __hip_atomic_fetch_add(&bar[1], 1u, __ATOMIC_ACQ_REL,
                                   __HIP_MEMORY_SCOPE_AGENT);
        } else {
            while (__hip_atomic_load(&bar[1], __ATOMIC_ACQUIRE,
                                     __HIP_MEMORY_SCOPE_AGENT) == gen) {}
        }
        __threadfence();
    }
    __syncthreads();

    // ================= phase 2: flash attention (r6 core) ==================
    const int half = wave >> 2;    // K half: keys [half*2048, +2048)
    const int qs = wave & 3;       // query subset (32 q)
    const int wv = wave & 3;       // staging sub-wave within half cohort

    // ---- Q fragments from swizzled LDS (32 queries) ----
    const int qrow2 = qs * 32 + l31;
    const char* qlp = (const char*)q_lds + qrow2 * 256;
    v8s qf[8];
#pragma unroll
    for (int kc = 0; kc < 8; ++kc)
        qf[kc] = *(const v8s*)(qlp + (((2 * kc + hi) ^ (qrow2 & 7)) << 4));

    v16f o[4];
#pragma unroll
    for (int fg = 0; fg < 4; ++fg)
#pragma unroll
        for (int r = 0; r < 16; ++r) o[fg][r] = 0.f;
    float lp = 0.f;

    // ---- LDS read bases (byte offsets; swizzle fields XOR-composable) ----
    // K: row = sub*32+l31 (256 B rows), slot = (2kc+hi) ^ (l31&15)
    const int kro = half * 32768 + l31 * 256 + ((hi ^ (l31 & 15)) << 4);
    // V: row a = fg*32+l31 (128 B rows), slot = (4sub+2g+hi) ^ (l31&7)
    const int vro = half * 32768 + l31 * 128 + (((l31 & 7) ^ hi) << 4);

    // ---- GLDS per-lane pre-swizzled sources ----
    // K: lane covers (row = krow+it*16, slot = lane&15); chunk = slot^(row&15)
    const int krow = wv * 4 + (lane >> 4);            // row&15, const over it
    const unsigned short* ksrc =
        ko + ((size_t)(b * SS + half * HKEYS) + krow) * DD +
        (((lane & 15) ^ krow) << 3);
    // V: lane covers (row = wv*8+it*32+vrow, slot = lane&7); chunk = slot^(row&7)
    const int vrow = lane >> 3;                       // row&7, const over it
    const unsigned short* vsrc =
        vo + (size_t)b * DD * SS + (size_t)(wv * 8 + vrow) * SS + half * HKEYS +
        (((lane & 7) ^ vrow) << 3);
    unsigned short* kd0 = &k_lds[half][0][wv * 512];  // wv*4 rows * 128
    unsigned short* vd0 = &v_lds[half][0][wv * 512];  // wv*8 rows * 64

    auto stage = [&](int p, int t) {
        unsigned short* kd = kd0 + p * 8192;
        unsigned short* vd = vd0 + p * 8192;
        const unsigned short* ks = ksrc + (size_t)t * 64 * DD;
        const unsigned short* vs = vsrc + t * 64;
#pragma unroll
        for (int it = 0; it < 4; ++it)
            GLDS16(ks + (size_t)it * 16 * DD, kd + it * 2048);
#pragma unroll
        for (int it = 0; it < 4; ++it)
            GLDS16(vs + (size_t)it * 32 * SS, vd + it * 2048);
    };

    auto compute = [&](int p, int sub) {
        const int ka = kro + p * 16384 + sub * 8192;
        v16f s;
#pragma unroll
        for (int r = 0; r < 16; ++r) s[r] = 0.f;
#pragma unroll
        for (int kc = 0; kc < 8; ++kc) {
            v8s af = *(const v8s*)((const char*)k_lds + (ka ^ (kc << 5)));
            s = MFMA32(af, qf[kc], s);
        }
        float e[16];
#pragma unroll
        for (int r = 0; r < 16; ++r) e[r] = EXP2F(s[r]);
        lp += (((e[0] + e[1]) + (e[2] + e[3])) + ((e[4] + e[5]) + (e[6] + e[7]))) +
              (((e[8] + e[9]) + (e[10] + e[11])) + ((e[12] + e[13]) + (e[14] + e[15])));
        union { v8s v[2]; unsigned int u[8]; } P;
#pragma unroll
        for (int g = 0; g < 2; ++g)
#pragma unroll
            for (int m = 0; m < 4; ++m)
                P.u[g * 4 + m] = pk_bf16(e[2 * m + 8 * g], e[2 * m + 8 * g + 1]);
        const int vb2 = (vro + p * 16384) ^ (sub << 6);
#pragma unroll
        for (int g = 0; g < 2; ++g) {
            const int vg = vb2 ^ (g << 5);            // chunk = 4sub + 2g + hi
#pragma unroll
            for (int fg = 0; fg < 4; ++fg) {
                v8s bf = *(const v8s*)((const char*)v_lds + (vg + fg * 4096));
                o[fg] = MFMA32(P.v[g], bf, o[fg]);
            }
        }
    };

    // ---- pipeline: counted vmcnt (8 GLDS/wave/tile), 2 barriers per 64 keys
    stage(0, 0);
#pragma unroll 1
    for (int t = 0; t < NT; t += 2) {
        stage(1, t + 1);
        WAITVM(8);          // tile-t (buf0) landed; t+1's 8 stay in flight
        BAR();
        compute(0, 0);
        compute(0, 1);
        WAITLGKM();
        BAR();              // everyone done reading buf0
        if (t + 2 < NT) {
            stage(0, t + 2);
            WAITVM(8);      // tile-(t+1) landed; t+2 in flight
        } else {
            WAITVM(0);
        }
        BAR();
        compute(1, 0);
        compute(1, 1);
        WAITLGKM();
        BAR();
    }

    // ---- epilogue: merge 2 halves (plain add: uniform softmax scale) ----
    lp += __shfl_xor(lp, 32);
    float* xl = (float*)q_lds;             // q_lds dead after qf loads
    if (hi == 0) xl[wave * 32 + l31] = lp;

    float* kf = (float*)&k_lds[0][0][0];   // 16384 floats: 4 regions of 4096

    auto putO = [&](float* base) {
#pragma unroll
        for (int fg = 0; fg < 4; ++fg) {
            v4f* bp = (v4f*)(base + fg * 1024 + lane * 16);
#pragma unroll
            for (int c = 0; c < 4; ++c) {
                v4f tv = {o[fg][c * 4 + 0], o[fg][c * 4 + 1],
                          o[fg][c * 4 + 2], o[fg][c * 4 + 3]};
                bp[c ^ (lane & 3)] = tv;
            }
        }
    };
    auto addO = [&](const float* base) {
#pragma unroll
        for (int fg = 0; fg < 4; ++fg) {
            const v4f* bp = (const v4f*)(base + fg * 1024 + lane * 16);
#pragma unroll
            for (int c = 0; c < 4; ++c) {
                v4f tv = bp[c ^ (lane & 3)];
#pragma unroll
                for (int j = 0; j < 4; ++j) o[fg][c * 4 + j] += tv[j];
            }
        }
    };

    if (half == 1) putO(kf + qs * 4096);
    __syncthreads();
    if (half == 0) {
        addO(kf + qs * 4096);
        float ir[16];
#pragma unroll
        for (int r = 0; r < 16; ++r) {
            int qr = (r & 3) + 8 * (r >> 2) + 4 * hi;
            ir[r] = 1.0f / (xl[qs * 32 + qr] + xl[(4 + qs) * 32 + qr]);
        }
#pragma unroll
        for (int fg = 0; fg < 4; ++fg)
#pragma unroll
            for (int r = 0; r < 16; ++r) {
                int qr = (r & 3) + 8 * (r >> 2) + 4 * hi;
                outp[(size_t)(b * SS + qbase + qs * 32 + qr) * DD +
                     fg * 32 + l31] = o[fg][r] * ir[r];
            }
    }
}

extern "C" void kernel_launch(void* const* d_in, const int* in_sizes, int n_in,
                              void* d_out, int out_size, void* d_ws, size_t ws_size,
                              hipStream_t stream)
{
    const float* x  = (const float*)d_in[0];
    const float* Wq = (const float*)d_in[1];
    const float* bq = (const float*)d_in[2];
    const float* Wk = (const float*)d_in[3];
    const float* bk = (const float*)d_in[4];
    const float* Wv = (const float*)d_in[5];
    const float* bv = (const float*)d_in[6];
    float* out = (float*)d_out;

    unsigned short* ko = (unsigned short*)d_ws;
    unsigned short* vo = ko + (size_t)BB * SS * DD;       // [B][A][S] frag-ordered
    unsigned int* bar = (unsigned int*)(vo + (size_t)BB * SS * DD);

    hipMemsetAsync(bar, 0, 8, stream);   // barrier state (workspace may be poisoned)
    hipLaunchKernelGGL(fused_kernel, dim3(BB * SS / 128), dim3(512), 0, stream,
                       x, Wq, bq, Wk, bk, Wv, bv, ko, vo, out, bar);
}

// Round 8
// 201.308 us; speedup vs baseline: 1.0207x; 1.0207x over previous
//
#include <hip/hip_runtime.h>

#define BB 8
#define SS 4096
#define DD 128

typedef __attribute__((ext_vector_type(8))) short v8s;
typedef __attribute__((ext_vector_type(4))) float v4f;
typedef __attribute__((ext_vector_type(16))) float v16f;

__device__ __forceinline__ unsigned short f2bf(float f) {
    unsigned int u = __float_as_uint(f);
    u += 0x7fffu + ((u >> 16) & 1u);
    return (unsigned short)(u >> 16);
}
// pack bf16(a) | bf16(b)<<16, round-half-up, via v_perm
__device__ __forceinline__ unsigned int pk_bf16(float a, float b) {
    unsigned int ua = __float_as_uint(a) + 0x8000u;
    unsigned int ub = __float_as_uint(b) + 0x8000u;
    return __builtin_amdgcn_perm(ub, ua, 0x07060302u);
}

#if !defined(__HIP_DEVICE_COMPILE__)
#define MFMA16(a, b, c) (c)
#define MFMA32(a, b, c) (c)
#define GLDS16(g, l)
#define WAITVM(n)
#define WAITLGKM()
#define BAR()
#else
#define MFMA16(a, b, c) __builtin_amdgcn_mfma_f32_16x16x32_bf16((a), (b), (c), 0, 0, 0)
#define MFMA32(a, b, c) __builtin_amdgcn_mfma_f32_32x32x16_bf16((a), (b), (c), 0, 0, 0)
// async global->LDS DMA, 16B/lane, LDS dest = uniform base + lane*16
#define GLDS16(g, l)                                                         \
    __builtin_amdgcn_global_load_lds(                                        \
        (const __attribute__((address_space(1))) unsigned int*)(g),          \
        (__attribute__((address_space(3))) unsigned int*)(l), 16, 0, 0)
#define WAITVM(n) asm volatile("s_waitcnt vmcnt(" #n ")" ::: "memory")
#define WAITLGKM() asm volatile("s_waitcnt lgkmcnt(0)" ::: "memory")
#define BAR()                                                                \
    do {                                                                     \
        asm volatile("" ::: "memory");                                       \
        __builtin_amdgcn_s_barrier();                                        \
        __builtin_amdgcn_sched_barrier(0);                                   \
        asm volatile("" ::: "memory");                                       \
    } while (0)
#endif

#if !defined(__HIP_DEVICE_COMPILE__)
#define EXP2F(x) exp2f(x)
#elif __has_builtin(__builtin_amdgcn_exp2f)
#define EXP2F(x) __builtin_amdgcn_exp2f(x)
#else
#define EXP2F(x) exp2f(x)
#endif

// (1/sqrt(128)) * log2(e): softmax in 2^x domain (no max subtraction: scores
// in log2 domain ~N(0,~6^2), fp32 overflow needs >20 sigma; the uniform
// scale cancels exactly in O/l). Both K-halves share the scale -> merging
// partial O/l is a plain add.
#define QSCALE 0.12751743f

// ---------------- kernel 0: W transpose (r6-verified verbatim) -------------
__global__ __launch_bounds__(256) void prep_kernel(
    const float* __restrict__ Wq, const float* __restrict__ Wk,
    const float* __restrict__ Wv, unsigned short* __restrict__ Wt)
{
    int id = blockIdx.x * 256 + threadIdx.x;
    int w = id >> 14;
    int n = (id >> 7) & 127;
    int k = id & 127;
    const float* W = (w == 0) ? Wq : (w == 1) ? Wk : Wv;
    Wt[id] = f2bf(W[k * 128 + n]);
}

// ---------------- kernel 1: projections, ALL 3 matrices per block ----------
// r6 proj bodies verbatim, but one block now owns 64 rows and loops over the
// 3 matrices: x read + pe trig done ONCE (r6 did both 3x via 3 blocks/row-
// group). vT written in MFMA-B-fragment key order (quadp, r6-verified).
__global__ __launch_bounds__(256, 2) void proj_kernel(
    const float* __restrict__ x, const unsigned short* __restrict__ Wt,
    const float* __restrict__ bq, const float* __restrict__ bk,
    const float* __restrict__ bv,
    unsigned short* __restrict__ qo, unsigned short* __restrict__ ko,
    unsigned short* __restrict__ vo)
{
    __shared__ __attribute__((aligned(16))) unsigned short w_lds[128 * 136]; // 34816 B
    __shared__ __attribute__((aligned(16))) unsigned short o_lds[9216];      // 18432 B

    const int tid = threadIdx.x;
    const int wave = tid >> 6;
    const int lane = tid & 63;
    const int quad = lane >> 4;
    const int l15 = lane & 15;
    const int rbase = blockIdx.x * 64;

    const int flatrow = rbase + wave * 16 + l15;
    const int srow = flatrow & 4095;
    v8s af[4];
#pragma unroll
    for (int kc = 0; kc < 4; ++kc) {
        const int kbase = kc * 32 + quad * 8;
        const v4f* xp = (const v4f*)(x + (size_t)flatrow * DD + kbase);
        v4f x0 = xp[0], x1 = xp[1];
        float p[8];
#pragma unroll
        for (int j = 0; j < 8; j += 2) {
            float freq = __expf((float)(kbase + j) * -0.07195578415606394f);
            float arg = (float)srow * freq;
            p[j] = __sinf(arg);
            p[j + 1] = __cosf(arg);
        }
        v8s a;
#pragma unroll
        for (int j = 0; j < 4; ++j) a[j] = (short)f2bf(x0[j] + p[j]);
#pragma unroll
        for (int j = 0; j < 4; ++j) a[4 + j] = (short)f2bf(x1[j] + p[4 + j]);
        af[kc] = a;
    }

    const int quadp = ((quad & 1) << 1) | (quad >> 1);

#pragma unroll 1
    for (int m = 0; m < 3; ++m) {
        const float* bias = (m == 0) ? bq : (m == 1) ? bk : bv;
        __syncthreads();   // previous m's users of w_lds/o_lds done
        const unsigned short* Wp = Wt + (m << 14);
#pragma unroll
        for (int it = 0; it < 8; ++it) {
            int id = it * 256 + tid;
            int n = id >> 4, c8 = id & 15;
            *(v8s*)(w_lds + n * 136 + c8 * 8) = *(const v8s*)(Wp + n * 128 + c8 * 8);
        }
        __syncthreads();   // w_lds ready

#pragma unroll
        for (int nb = 0; nb < 8; ++nb) {
            const int col = nb * 16 + l15;
            v4f acc = {0.f, 0.f, 0.f, 0.f};
#pragma unroll
            for (int kc = 0; kc < 4; ++kc) {
                v8s bf = *(const v8s*)(w_lds + col * 136 + kc * 32 + quad * 8);
                acc = MFMA16(af[kc], bf, acc);
            }
            float bval = bias[col];
#pragma unroll
            for (int reg = 0; reg < 4; ++reg) {
                float val = acc[reg] + bval;
                if (m == 0) {
                    int lr = wave * 16 + quad * 4 + reg;
                    o_lds[lr * 136 + col] = f2bf(val * QSCALE);
                } else if (m == 1) {
                    int lr = wave * 16 + quad * 4 + reg;
                    o_lds[lr * 136 + col] = f2bf(val);
                } else {
                    int plr = wave * 16 + quadp * 4 + reg;   // fragment-order key
                    o_lds[col * 72 + plr] = f2bf(val);       // transpose for vT
                }
            }
        }
        __syncthreads();   // o_lds ready

        if (m <= 1) {
            unsigned short* outp = (m == 0) ? qo : ko;
#pragma unroll
            for (int it = 0; it < 4; ++it) {
                int id = it * 256 + tid;
                int r = id >> 4, c8 = id & 15;
                *(v8s*)(outp + (size_t)(rbase + r) * DD + c8 * 8) =
                    *(const v8s*)(o_lds + r * 136 + c8 * 8);
            }
        } else {
            const int b0 = rbase >> 12, s0 = rbase & 4095;
#pragma unroll
            for (int it = 0; it < 4; ++it) {
                int id = it * 256 + tid;
                int a = id >> 3, c = id & 7;
                *(v8s*)(vo + ((size_t)(b0 * 128 + a)) * SS + s0 + c * 8) =
                    *(const v8s*)(o_lds + a * 72 + c * 8);
            }
        }
    }
}

// ---------------- kernel 2: flash attention, desynced half-blocks ----------
// 512 blocks x 256 thr (4 waves): block = (b, qt, half) owns 128 q x 2048
// keys. Inner code = r6-verified (same staging cohort geometry, swizzles,
// counted-vmcnt pipeline, NT=32). LDS 66KB -> TWO independent blocks/CU:
// same 8 waves/CU as r6, but the two blocks' barriers are decoupled, so one
// block's MFMA overlaps the other's LDS/DMA/VALU (m114 wave-overlap) instead
// of r6's 8-wave lockstep serialization. Halves merge via global partial-O
// (f32) + per-pair release/acquire flag; pair shares an XCD (bid%8 = b).
#define HKEYS 2048
#define NT 32             // 64-key tiles per half
__global__ __launch_bounds__(256, 2) void flash_kernel(
    const unsigned short* __restrict__ qp,
    const unsigned short* __restrict__ kp,
    const unsigned short* __restrict__ vp,   // [B][A][S], fragment-ordered keys
    float* __restrict__ op_part, float* __restrict__ lp_part,
    unsigned int* __restrict__ flags,
    float* __restrict__ outp)
{
    __shared__ __attribute__((aligned(16))) unsigned short k_lds[2][8192]; // 32 KB
    __shared__ __attribute__((aligned(16))) unsigned short v_lds[2][8192]; // 32 KB
    __shared__ float xl[128];                                              // 512 B

    const int tid = threadIdx.x;
    const int wave = tid >> 6;
    const int lane = tid & 63;
    const int hi = lane >> 5;
    const int l31 = lane & 31;
    const int bid = blockIdx.x;
    const int b = bid & 7;             // batch -> XCD pinning (pair co-located)
    const int half = (bid >> 3) & 1;   // K half: keys [half*2048, +2048)
    const int qt = bid >> 4;
    const int qbase = qt * 128;
    const int qs = wave;               // query subset (32 q)
    const int wv = wave;               // staging sub-wave

    // ---- Q fragments (32 queries) ----
    const size_t qrow = (size_t)(b * SS + qbase + qs * 32 + l31) * DD;
    v8s qf[8];
#pragma unroll
    for (int kc = 0; kc < 8; ++kc)
        qf[kc] = *(const v8s*)(qp + qrow + kc * 16 + hi * 8);

    v16f o[4];
#pragma unroll
    for (int fg = 0; fg < 4; ++fg)
#pragma unroll
        for (int r = 0; r < 16; ++r) o[fg][r] = 0.f;
    float lp = 0.f;

    // ---- LDS read bases (r6 formulas, block-level half) ----
    // K: row = sub*32+l31 (256 B rows), slot = (2kc+hi) ^ (l31&15)
    const int kro = l31 * 256 + ((hi ^ (l31 & 15)) << 4);
    // V: row a = fg*32+l31 (128 B rows), slot = (4sub+2g+hi) ^ (l31&7)
    const int vro = l31 * 128 + (((l31 & 7) ^ hi) << 4);

    // ---- GLDS per-lane pre-swizzled sources (r6 verbatim) ----
    const int krow = wv * 4 + (lane >> 4);            // row&15, const over it
    const unsigned short* ksrc =
        kp + ((size_t)(b * SS + half * HKEYS) + krow) * DD +
        (((lane & 15) ^ krow) << 3);
    const int vrow = lane >> 3;                       // row&7, const over it
    const unsigned short* vsrc =
        vp + (size_t)b * DD * SS + (size_t)(wv * 8 + vrow) * SS + half * HKEYS +
        (((lane & 7) ^ vrow) << 3);
    unsigned short* kd0 = &k_lds[0][wv * 512];
    unsigned short* vd0 = &v_lds[0][wv * 512];

    auto stage = [&](int p, int t) {
        unsigned short* kd = kd0 + p * 8192;
        unsigned short* vd = vd0 + p * 8192;
        const unsigned short* ks = ksrc + (size_t)t * 64 * DD;
        const unsigned short* vs = vsrc + t * 64;
#pragma unroll
        for (int it = 0; it < 4; ++it)
            GLDS16(ks + (size_t)it * 16 * DD, kd + it * 2048);
#pragma unroll
        for (int it = 0; it < 4; ++it)
            GLDS16(vs + (size_t)it * 32 * SS, vd + it * 2048);
    };

    auto compute = [&](int p, int sub) {
        const int ka = kro + p * 16384 + sub * 8192;
        v16f s;
#pragma unroll
        for (int r = 0; r < 16; ++r) s[r] = 0.f;
#pragma unroll
        for (int kc = 0; kc < 8; ++kc) {
            v8s af = *(const v8s*)((const char*)k_lds + (ka ^ (kc << 5)));
            s = MFMA32(af, qf[kc], s);
        }
        float e[16];
#pragma unroll
        for (int r = 0; r < 16; ++r) e[r] = EXP2F(s[r]);
        lp += (((e[0] + e[1]) + (e[2] + e[3])) + ((e[4] + e[5]) + (e[6] + e[7]))) +
              (((e[8] + e[9]) + (e[10] + e[11])) + ((e[12] + e[13]) + (e[14] + e[15])));
        union { v8s v[2]; unsigned int u[8]; } P;
#pragma unroll
        for (int g = 0; g < 2; ++g)
#pragma unroll
            for (int m = 0; m < 4; ++m)
                P.u[g * 4 + m] = pk_bf16(e[2 * m + 8 * g], e[2 * m + 8 * g + 1]);
        const int vb2 = (vro + p * 16384) ^ (sub << 6);
#pragma unroll
        for (int g = 0; g < 2; ++g) {
            const int vg = vb2 ^ (g << 5);            // chunk = 4sub + 2g + hi
#pragma unroll
            for (int fg = 0; fg < 4; ++fg) {
                v8s bf = *(const v8s*)((const char*)v_lds + (vg + fg * 4096));
                o[fg] = MFMA32(P.v[g], bf, o[fg]);
            }
        }
    };

    // ---- pipeline: counted vmcnt (8 GLDS/wave/tile), 2 barriers / 64 keys
    stage(0, 0);
#pragma unroll 1
    for (int t = 0; t < NT; t += 2) {
        stage(1, t + 1);
        WAITVM(8);          // tile-t (buf0) landed; t+1's 8 stay in flight
        BAR();
        compute(0, 0);
        compute(0, 1);
        WAITLGKM();
        BAR();              // everyone done reading buf0
        if (t + 2 < NT) {
            stage(0, t + 2);
            WAITVM(8);      // tile-(t+1) landed; t+2 in flight
        } else {
            WAITVM(0);
        }
        BAR();
        compute(1, 0);
        compute(1, 1);
        WAITLGKM();
        BAR();
    }

    // ---- epilogue: cross-block half merge (plain add: uniform scale) ----
    lp += __shfl_xor(lp, 32);
    const int pairIdx = qt * 8 + b;
    float* OP = op_part + (size_t)pairIdx * 16384;
    float* LP = lp_part + pairIdx * 128;

    if (half == 1) {
#pragma unroll
        for (int fg = 0; fg < 4; ++fg)
#pragma unroll
            for (int r = 0; r < 16; ++r) {
                int qr = (r & 3) + 8 * (r >> 2) + 4 * hi;
                OP[(qs * 32 + qr) * 128 + fg * 32 + l31] = o[fg][r];
            }
        if (hi == 0) LP[qs * 32 + l31] = lp;
        WAITVM(0);              // partial stores drained
        __syncthreads();        // whole block done
        if (tid == 0) {
            __threadfence();
            __hip_atomic_store(&flags[pairIdx], 1u, __ATOMIC_RELEASE,
                               __HIP_MEMORY_SCOPE_AGENT);
        }
    } else {
        if (hi == 0) xl[qs * 32 + l31] = lp;
        if (tid == 0) {
            while (__hip_atomic_load(&flags[pairIdx], __ATOMIC_ACQUIRE,
                                     __HIP_MEMORY_SCOPE_AGENT) == 0u)
                __builtin_amdgcn_s_sleep(2);
            __threadfence();    // L1-invalidate before block reads partials
        }
        __syncthreads();        // partner data + xl visible to all waves
        float ir[16];
#pragma unroll
        for (int r = 0; r < 16; ++r) {
            int qr = (r & 3) + 8 * (r >> 2) + 4 * hi;
            ir[r] = 1.0f / (xl[qs * 32 + qr] + LP[qs * 32 + qr]);
        }
#pragma unroll
        for (int fg = 0; fg < 4; ++fg)
#pragma unroll
            for (int r = 0; r < 16; ++r) {
                int qr = (r & 3) + 8 * (r >> 2) + 4 * hi;
                outp[(size_t)(b * SS + qbase + qs * 32 + qr) * DD + fg * 32 + l31] =
                    (o[fg][r] + OP[(qs * 32 + qr) * 128 + fg * 32 + l31]) * ir[r];
            }
    }
}

extern "C" void kernel_launch(void* const* d_in, const int* in_sizes, int n_in,
                              void* d_out, int out_size, void* d_ws, size_t ws_size,
                              hipStream_t stream)
{
    const float* x  = (const float*)d_in[0];
    const float* Wq = (const float*)d_in[1];
    const float* bq = (const float*)d_in[2];
    const float* Wk = (const float*)d_in[3];
    const float* bk = (const float*)d_in[4];
    const float* Wv = (const float*)d_in[5];
    const float* bv = (const float*)d_in[6];
    float* out = (float*)d_out;

    unsigned short* Wt = (unsigned short*)d_ws;                  // 49152 shorts
    unsigned short* q  = Wt + 49152;
    unsigned short* k  = q + (size_t)BB * SS * DD;
    unsigned short* vT = k + (size_t)BB * SS * DD;               // [B][A][S]
    float* op_part = (float*)(vT + (size_t)BB * SS * DD);        // 256*16384 f32
    float* lp_part = op_part + (size_t)256 * 16384;              // 32768 f32
    unsigned int* flags = (unsigned int*)(lp_part + 32768);      // 256 u32

    hipMemsetAsync(flags, 0, 256 * sizeof(unsigned int), stream);
    hipLaunchKernelGGL(prep_kernel, dim3(192), dim3(256), 0, stream,
                       Wq, Wk, Wv, Wt);
    hipLaunchKernelGGL(proj_kernel, dim3(BB * SS / 64), dim3(256), 0, stream,
                       x, Wt, bq, bk, bv, q, k, vT);
    hipLaunchKernelGGL(flash_kernel, dim3(BB * SS / 64), dim3(256), 0, stream,
                       q, k, vT, op_part, lp_part, flags, out);
}